// Round 8
// baseline (104.906 us; speedup 1.0000x reference)
//
#include <hip/hip_runtime.h>
#include <stdint.h>
#include <stddef.h>

typedef __bf16 bf16_t;
typedef __bf16 bf16x8 __attribute__((ext_vector_type(8)));
typedef float  f32x4  __attribute__((ext_vector_type(4)));

#define NIMG 16
#define CIN  128
#define COUT 128
#define HH   56
#define WW   56
#define HW   (HH * WW)       // 3136
#define PRW  58              // padded rows / cols
#define ROWPAIRS 28
// P layout (uint4 units of 8 bf16 along ci): unit = ((n*58 + r)*16 + cig)*58 + c
//   -> a conv block's 4-row window (r = h0..h0+3) is ONE contiguous 3712-unit span.

// ---------- prologue 1: W[co][ci][3][3] fp32 -> Wt2 fragment-major bf16 ----------
// rec = (khkw*4+chunk)*8 + (co>>4); element (lane=l4*16+l15, j) =
//   W[co=(co>>4)*16+l15][ci=chunk*32+l4*8+j][khkw]   (1 KB lane-contiguous bursts)
__global__ void wtrans_kernel(const float* __restrict__ w, bf16_t* __restrict__ wt2) {
    int idx = blockIdx.x * 256 + threadIdx.x;    // 16384 threads: one (co,ci) each
    int co = idx >> 7, ci = idx & 127;
    const float* src = w + (size_t)idx * 9;
    float v[9];
#pragma unroll
    for (int k = 0; k < 9; ++k) v[k] = src[k];
    int chunk = ci >> 5, l4 = (ci >> 3) & 3, j = ci & 7;
    int cotile = co >> 4, l15 = co & 15;
    int lane = l4 * 16 + l15;
#pragma unroll
    for (int k = 0; k < 9; ++k) {
        size_t rec = (size_t)((k * 4 + chunk) * 8 + cotile);
        wt2[rec * 512 + lane * 8 + j] = (bf16_t)v[k];
    }
}

// ---------- prologue 2: fp32 NCHW -> P (bf16, padded, conv-LDS layout) ----------
__global__ void itrans_kernel(const float* __restrict__ in, uint4* __restrict__ P) {
    int idx = blockIdx.x * 256 + threadIdx.x;    // 3364*256 = 861184 exactly
    int c   = idx % PRW;                         // fastest -> contiguous P writes
    int t1  = idx / PRW;
    int cig = t1 & 15;
    int t2  = t1 >> 4;
    int r   = t2 % PRW;
    int n   = t2 / PRW;

    uint32_t u[8];
    if (r >= 1 && r <= HH && c >= 1 && c <= WW) {
        const float* src = in + (((size_t)n * CIN + cig * 8) * HH + (r - 1)) * WW + (c - 1);
        float v[8];
#pragma unroll
        for (int j = 0; j < 8; ++j) v[j] = src[(size_t)j * HW];  // 8 independent strided loads
#pragma unroll
        for (int j = 0; j < 8; ++j) { bf16_t b = (bf16_t)v[j]; u[j] = *(const uint16_t*)&b; }
    } else {
#pragma unroll
        for (int j = 0; j < 8; ++j) u[j] = 0;
    }
    uint4 o;
    o.x = u[0] | (u[1] << 16); o.y = u[2] | (u[3] << 16);
    o.z = u[4] | (u[5] << 16); o.w = u[6] | (u[7] << 16);
    P[idx] = o;
}

// ---------- fused conv: block = (n, 2 rows) x 128 co; 512 thr = 8 waves ----------
// wave = ks*4 + wc*2 + ws: tile 64sp x 64co (tc=4, ts=4), K split by ks.
// Staging: 15 async global_load_lds dwordx4 per block (contiguous P span). One barrier.
// LDS bf16 offset for (rr, cig, c): ((rr*16 + cig)*58 + c)*8
#define FRAG_OFF(I) ((size_t)((((I) >> 1) * 4 + ((I) & 1)) * 8) * 512)

#define DO_PHASE(I, F0, F1, F2, F3) do {                                             \
    const int kh_ = ((I) >> 1) / 3, kw_ = ((I) >> 1) % 3;                            \
    const bf16_t* lb_ = inp + (size_t)(((ws + kh_) * 16 + (ks * 2 + ((I) & 1)) * 4 + l4) * 58) * 8; \
    _Pragma("unroll")                                                                \
    for (int ts = 0; ts < 4; ++ts) {                                                 \
        int cb_ = ts * 16 + l15 + kw_;                                               \
        if (cb_ > 57) cb_ = 57;   /* only lanes whose outputs are discarded */       \
        bf16x8 bfm_ = *(const bf16x8*)(lb_ + (size_t)cb_ * 8);                       \
        acc[0][ts] = __builtin_amdgcn_mfma_f32_16x16x32_bf16(F0, bfm_, acc[0][ts], 0, 0, 0); \
        acc[1][ts] = __builtin_amdgcn_mfma_f32_16x16x32_bf16(F1, bfm_, acc[1][ts], 0, 0, 0); \
        acc[2][ts] = __builtin_amdgcn_mfma_f32_16x16x32_bf16(F2, bfm_, acc[2][ts], 0, 0, 0); \
        acc[3][ts] = __builtin_amdgcn_mfma_f32_16x16x32_bf16(F3, bfm_, acc[3][ts], 0, 0, 0); \
    }                                                                                \
} while (0)

#define PREFETCH(I, F0, F1, F2, F3) do {                                             \
    const bf16_t* wp_ = wpbase + FRAG_OFF(I);                                        \
    F0 = *(const bf16x8*)(wp_);                                                      \
    F1 = *(const bf16x8*)(wp_ + 512);                                                \
    F2 = *(const bf16x8*)(wp_ + 1024);                                               \
    F3 = *(const bf16x8*)(wp_ + 1536);                                               \
} while (0)

__global__ __launch_bounds__(512, 4)
void conv_fused_kernel(const uint4* __restrict__ P, const bf16_t* __restrict__ Wt2,
                       const float* __restrict__ bias, float* __restrict__ out) {
    __shared__ __align__(16) unsigned char smem[65536];  // stage 59392 B / reduce 65536 B
    bf16_t* inp = (bf16_t*)smem;

    const int bx = blockIdx.x;
    const int n  = bx / ROWPAIRS;
    const int h0 = (bx % ROWPAIRS) * 2;          // padded rows h0..h0+3 (always in range)

    const int tid  = threadIdx.x;
    const int lane = tid & 63;
    const int wave = tid >> 6;                   // 0..7
    const int ws  = wave & 1;                    // output row within pair
    const int wc  = (wave >> 1) & 1;             // co half (64)
    const int ks  = wave >> 2;                   // K half (chunks 2ks, 2ks+1)
    const int l15 = lane & 15;
    const int l4  = lane >> 4;

    // ---- async DMA stage: 3712 contiguous uint4 from P -> LDS (identical layout)
    const uint4* Pt = P + ((size_t)n * PRW + h0) * (16 * PRW);
#pragma unroll
    for (int it = 0; it < 15; ++it) {
        int ub = it * 256 + wave * 64;           // wave-uniform LDS/global chunk base
        int u  = ub + lane;
        if (u < 3712)
            __builtin_amdgcn_global_load_lds((const uint32_t*)(Pt + u),
                                             (uint32_t*)(smem + (size_t)ub * 16), 16, 0, 0);
    }
    __syncthreads();                             // drains vmcnt; LDS tile ready

    f32x4 acc[4][4];                             // [co tile][sp tile]
#pragma unroll
    for (int a = 0; a < 4; ++a)
#pragma unroll
        for (int b2 = 0; b2 < 4; ++b2) acc[a][b2] = (f32x4){0.f, 0.f, 0.f, 0.f};

    // weight fragment base: rec = (khkw*4 + ks*2 + cs)*8 + wc*4 + tc
    const bf16_t* wpbase = Wt2 + (size_t)(ks * 16 + wc * 4) * 512 + (size_t)lane * 8;

    bf16x8 A0, A1, A2, A3, B0, B1, B2, B3;       // named regs, prefetch distance 2
    PREFETCH(0, A0, A1, A2, A3);
    PREFETCH(1, B0, B1, B2, B3);

#pragma unroll
    for (int ii = 0; ii < 8; ++ii) {
        const int i0 = ii * 2;
        DO_PHASE(i0, A0, A1, A2, A3);
        PREFETCH(i0 + 2, A0, A1, A2, A3);
        DO_PHASE(i0 + 1, B0, B1, B2, B3);
        PREFETCH(i0 + 3, B0, B1, B2, B3);
    }
    DO_PHASE(16, A0, A1, A2, A3);
    DO_PHASE(17, B0, B1, B2, B3);

    // ---- cross-wave K reduction through LDS (ks=1 -> ks=0)
    __syncthreads();                             // K-loop LDS reads done; safe to overwrite
    float* red = (float*)smem;
    const int q = wc * 2 + ws;                   // 0..3
    if (ks == 1) {
#pragma unroll
        for (int tc = 0; tc < 4; ++tc)
#pragma unroll
            for (int ts = 0; ts < 4; ++ts)
                *(f32x4*)(red + (size_t)q * 4096 + (tc * 4 + ts) * 256 + lane * 4) = acc[tc][ts];
    }
    __syncthreads();
    if (ks == 0) {
        const int h   = h0 + ws;
        const int co0 = wc * 64;
        float* obase = out + ((size_t)n * COUT) * HW + (size_t)h * WW;
#pragma unroll
        for (int tc = 0; tc < 4; ++tc) {
#pragma unroll
            for (int ts = 0; ts < 4; ++ts) {
                f32x4 oth = *(const f32x4*)(red + (size_t)q * 4096 + (tc * 4 + ts) * 256 + lane * 4);
                f32x4 r = acc[tc][ts] + oth;
                int w0 = ts * 16 + l15;
                if (w0 < WW) {
#pragma unroll
                    for (int i = 0; i < 4; ++i) {
                        int co = co0 + tc * 16 + l4 * 4 + i;
                        obase[(size_t)co * HW + w0] = r[i] + bias[co];
                    }
                }
            }
        }
    }
}

extern "C" void kernel_launch(void* const* d_in, const int* in_sizes, int n_in,
                              void* d_out, int out_size, void* d_ws, size_t ws_size,
                              hipStream_t stream) {
    const float* in   = (const float*)d_in[0];
    const float* wgt  = (const float*)d_in[1];
    const float* bias = (const float*)d_in[2];
    float* out = (float*)d_out;

    uint4* P = (uint4*)d_ws;                                    // 861184 units = 13,778,944 B
    bf16_t* Wt2 = (bf16_t*)((char*)d_ws + (size_t)861184 * 16); // +294,912 B, fragment-major

    wtrans_kernel<<<64, 256, 0, stream>>>(wgt, Wt2);
    itrans_kernel<<<3364, 256, 0, stream>>>(in, P);
    conv_fused_kernel<<<NIMG * ROWPAIRS, 512, 0, stream>>>(P, Wt2, bias, out);
}